// Round 2
// baseline (6628.817 us; speedup 1.0000x reference)
//
#include <hip/hip_runtime.h>
#include <hip/hip_bf16.h>
#include <math.h>

// Problem constants (from reference)
#define L_SEQ   2048
#define DM      768     // d_model
#define DIN     1536    // d_inner
#define NST     16      // ssm state size n
#define DTR     48      // dt_rank
#define XD      80      // dt_rank + 2n
#define DCONVK  4
#define NLAYERS 2
#define NVOCAB  32000

// ---------------------------------------------------------------------------
// Embedding gather: x[l,:] = emb[ids[l],:]
__global__ void embed_kernel(const int* __restrict__ ids,
                             const float* __restrict__ emb,
                             float* __restrict__ x) {
    int idx = blockIdx.x * 256 + threadIdx.x;          // L*DM total
    int l = idx / DM, j = idx % DM;
    x[idx] = emb[(size_t)ids[l] * DM + j];
}

// ---------------------------------------------------------------------------
// RMSNorm: one block per row of 768
__global__ __launch_bounds__(256) void rmsnorm_kernel(const float* __restrict__ x,
                                                      const float* __restrict__ w,
                                                      float* __restrict__ h) {
    int row = blockIdx.x, tid = threadIdx.x;
    __shared__ float red[256];
    const float* xrow = x + (size_t)row * DM;
    float ss = 0.f;
    for (int j = tid; j < DM; j += 256) { float v = xrow[j]; ss += v * v; }
    red[tid] = ss; __syncthreads();
    for (int s = 128; s > 0; s >>= 1) {
        if (tid < s) red[tid] += red[tid + s];
        __syncthreads();
    }
    float scale = rsqrtf(red[0] / (float)DM + 1e-5f);
    float* hrow = h + (size_t)row * DM;
    for (int j = tid; j < DM; j += 256) hrow[j] = xrow[j] * scale * w[j];
}

// ---------------------------------------------------------------------------
// Generic C = A * B^T GEMM (A: MxK lda, B: NoutxK ldb, both row-major).
// 64x64 block tile, 256 threads, 4x4 micro-tile per thread, K-tile 16.
// EPI: 0 = store, 1 = C += acc (residual), 2 = C = softplus(acc + bias[n])
template <int EPI>
__global__ __launch_bounds__(256) void gemm_tn(const float* __restrict__ A, int lda,
                                               const float* __restrict__ B, int ldb,
                                               float* __restrict__ C, int ldc,
                                               int M, int Nout, int K,
                                               const float* __restrict__ bias) {
    __shared__ float As[16][68];   // [k][m], +4 pad
    __shared__ float Bs[16][68];   // [k][n]
    int tid = threadIdx.x;
    int tx = tid & 15, ty = tid >> 4;
    int m0 = blockIdx.y * 64, n0 = blockIdx.x * 64;
    int lrow = tid >> 2, lkq = tid & 3;   // load: row 0..63, k-quad 0..3

    float acc[4][4] = {};

    for (int k0 = 0; k0 < K; k0 += 16) {
        float4 av = make_float4(0.f, 0.f, 0.f, 0.f);
        float4 bv = make_float4(0.f, 0.f, 0.f, 0.f);
        if (m0 + lrow < M)
            av = *(const float4*)&A[(size_t)(m0 + lrow) * lda + k0 + lkq * 4];
        if (n0 + lrow < Nout)
            bv = *(const float4*)&B[(size_t)(n0 + lrow) * ldb + k0 + lkq * 4];
        __syncthreads();   // protect previous iteration's LDS reads
        As[lkq * 4 + 0][lrow] = av.x; As[lkq * 4 + 1][lrow] = av.y;
        As[lkq * 4 + 2][lrow] = av.z; As[lkq * 4 + 3][lrow] = av.w;
        Bs[lkq * 4 + 0][lrow] = bv.x; Bs[lkq * 4 + 1][lrow] = bv.y;
        Bs[lkq * 4 + 2][lrow] = bv.z; Bs[lkq * 4 + 3][lrow] = bv.w;
        __syncthreads();
#pragma unroll
        for (int kk = 0; kk < 16; ++kk) {
            float4 a4 = *(const float4*)&As[kk][ty * 4];
            float4 b4 = *(const float4*)&Bs[kk][tx * 4];
            acc[0][0] += a4.x * b4.x; acc[0][1] += a4.x * b4.y;
            acc[0][2] += a4.x * b4.z; acc[0][3] += a4.x * b4.w;
            acc[1][0] += a4.y * b4.x; acc[1][1] += a4.y * b4.y;
            acc[1][2] += a4.y * b4.z; acc[1][3] += a4.y * b4.w;
            acc[2][0] += a4.z * b4.x; acc[2][1] += a4.z * b4.y;
            acc[2][2] += a4.z * b4.z; acc[2][3] += a4.z * b4.w;
            acc[3][0] += a4.w * b4.x; acc[3][1] += a4.w * b4.y;
            acc[3][2] += a4.w * b4.z; acc[3][3] += a4.w * b4.w;
        }
    }

#pragma unroll
    for (int i = 0; i < 4; ++i) {
        int m = m0 + ty * 4 + i;
        if (m >= M) continue;
#pragma unroll
        for (int j = 0; j < 4; ++j) {
            int n = n0 + tx * 4 + j;
            if (n >= Nout) continue;
            size_t ci = (size_t)m * ldc + n;
            float v = acc[i][j];
            if (EPI == 1) {
                C[ci] += v;
            } else if (EPI == 2) {
                float t = v + bias[n];
                // softplus(t) = max(t,0) + log1p(exp(-|t|))
                C[ci] = fmaxf(t, 0.f) + log1pf(__expf(-fabsf(t)));
            } else {
                C[ci] = v;
            }
        }
    }
}

// ---------------------------------------------------------------------------
// Causal depthwise conv1d (kernel 4, left pad 3) + SiLU.
// xs lives in xr[:, 0:DIN] (row stride 2*DIN).
__global__ void conv_silu_kernel(const float* __restrict__ xr,
                                 const float* __restrict__ cw,
                                 const float* __restrict__ cb,
                                 float* __restrict__ xc) {
    int idx = blockIdx.x * 256 + threadIdx.x;  // L*DIN
    int l = idx / DIN, d = idx % DIN;
    float acc = cb[d];
#pragma unroll
    for (int k = 0; k < DCONVK; ++k) {
        int ll = l + k - (DCONVK - 1);
        if (ll >= 0) acc += xr[(size_t)ll * (2 * DIN) + d] * cw[d * DCONVK + k];
    }
    float sg = 1.f / (1.f + __expf(-acc));
    xc[idx] = acc * sg;
}

// ---------------------------------------------------------------------------
// Selective scan, fused with y = (scan + u*D) * silu(res).
// One thread per channel d; 16 states in registers; B/C staged in LDS
// in 64-timestep chunks.
__global__ __launch_bounds__(256) void scan_kernel(const float* __restrict__ xc,     // u (L,DIN)
                                                   const float* __restrict__ delta,  // (L,DIN)
                                                   const float* __restrict__ xdbl,   // (L,XD) cols 48..79 = B,C
                                                   const float* __restrict__ A_log,  // (DIN,NST)
                                                   const float* __restrict__ Dp,     // (DIN,)
                                                   const float* __restrict__ xr,     // res at col DIN, stride 2*DIN
                                                   float* __restrict__ y) {          // (L,DIN)
    int d = blockIdx.x * 256 + threadIdx.x;
    float Arow[NST];
#pragma unroll
    for (int n = 0; n < NST; ++n) Arow[n] = -__expf(A_log[d * NST + n]);
    float Dd = Dp[d];
    float s[NST];
#pragma unroll
    for (int n = 0; n < NST; ++n) s[n] = 0.f;

    __shared__ float bc[64][32];   // [l_local][0:16=B, 16:32=C]
    for (int l0 = 0; l0 < L_SEQ; l0 += 64) {
        __syncthreads();
        for (int t = threadIdx.x; t < 64 * 32; t += 256) {
            int ll = t >> 5, j = t & 31;
            bc[ll][j] = xdbl[(size_t)(l0 + ll) * XD + DTR + j];
        }
        __syncthreads();
        for (int li = 0; li < 64; ++li) {
            int l = l0 + li;
            float dl = delta[(size_t)l * DIN + d];
            float u  = xc[(size_t)l * DIN + d];
            float du = dl * u;
            float accv = 0.f;
#pragma unroll
            for (int n = 0; n < NST; ++n) {
                float dA = __expf(dl * Arow[n]);
                s[n] = dA * s[n] + du * bc[li][n];
                accv += s[n] * bc[li][16 + n];
            }
            float rs = xr[(size_t)l * (2 * DIN) + DIN + d];
            float sg = 1.f / (1.f + __expf(-rs));
            y[(size_t)l * DIN + d] = (accv + u * Dd) * (rs * sg);
        }
    }
}

// ---------------------------------------------------------------------------
extern "C" void kernel_launch(void* const* d_in, const int* in_sizes, int n_in,
                              void* d_out, int out_size, void* d_ws, size_t ws_size,
                              hipStream_t stream) {
    const int*   ids        = (const int*)d_in[0];
    const float* emb        = (const float*)d_in[1];    // (VOCAB, DM)
    const float* norm_w     = (const float*)d_in[2];    // (NL, DM)
    const float* in_proj_w  = (const float*)d_in[3];    // (NL, 2*DIN, DM)
    const float* conv_w     = (const float*)d_in[4];    // (NL, DIN, 4)
    const float* conv_b     = (const float*)d_in[5];    // (NL, DIN)
    const float* x_proj_w   = (const float*)d_in[6];    // (NL, XD, DIN)
    const float* dt_proj_w  = (const float*)d_in[7];    // (NL, DIN, DTR)
    const float* dt_proj_b  = (const float*)d_in[8];    // (NL, DIN)
    const float* A_log      = (const float*)d_in[9];    // (NL, DIN, NST)
    const float* Dp         = (const float*)d_in[10];   // (NL, DIN)
    const float* out_proj_w = (const float*)d_in[11];   // (NL, DM, DIN)
    const float* norm_f_w   = (const float*)d_in[12];   // (DM,)
    float* out = (float*)d_out;                         // (L, VOCAB)

    float* ws    = (float*)d_ws;
    float* x     = ws;                                   // L*DM
    float* h     = x    + (size_t)L_SEQ * DM;            // L*DM
    float* xr    = h    + (size_t)L_SEQ * DM;            // L*2*DIN
    float* xc    = xr   + (size_t)L_SEQ * 2 * DIN;       // L*DIN
    float* xdbl  = xc   + (size_t)L_SEQ * DIN;           // L*XD
    float* delta = xdbl + (size_t)L_SEQ * XD;            // L*DIN
    float* y     = delta+ (size_t)L_SEQ * DIN;           // L*DIN

    embed_kernel<<<L_SEQ * DM / 256, 256, 0, stream>>>(ids, emb, x);

    for (int i = 0; i < NLAYERS; ++i) {
        rmsnorm_kernel<<<L_SEQ, 256, 0, stream>>>(x, norm_w + i * DM, h);

        // xr = h @ in_proj_w^T   (2048 x 3072, K=768)
        gemm_tn<0><<<dim3(2 * DIN / 64, L_SEQ / 64), 256, 0, stream>>>(
            h, DM, in_proj_w + (size_t)i * 2 * DIN * DM, DM,
            xr, 2 * DIN, L_SEQ, 2 * DIN, DM, nullptr);

        conv_silu_kernel<<<L_SEQ * DIN / 256, 256, 0, stream>>>(
            xr, conv_w + i * DIN * DCONVK, conv_b + i * DIN, xc);

        // xdbl = xc @ x_proj_w^T  (2048 x 80, K=1536)
        gemm_tn<0><<<dim3((XD + 63) / 64, L_SEQ / 64), 256, 0, stream>>>(
            xc, DIN, x_proj_w + (size_t)i * XD * DIN, DIN,
            xdbl, XD, L_SEQ, XD, DIN, nullptr);

        // delta = softplus(xdbl[:, :48] @ dt_proj_w^T + b)  (2048 x 1536, K=48)
        gemm_tn<2><<<dim3(DIN / 64, L_SEQ / 64), 256, 0, stream>>>(
            xdbl, XD, dt_proj_w + (size_t)i * DIN * DTR, DTR,
            delta, DIN, L_SEQ, DIN, DTR, dt_proj_b + i * DIN);

        scan_kernel<<<DIN / 256, 256, 0, stream>>>(
            xc, delta, xdbl, A_log + (size_t)i * DIN * NST, Dp + i * DIN, xr, y);

        // x += y @ out_proj_w^T  (2048 x 768, K=1536)
        gemm_tn<1><<<dim3(DM / 64, L_SEQ / 64), 256, 0, stream>>>(
            y, DIN, out_proj_w + (size_t)i * DM * DIN, DIN,
            x, DM, L_SEQ, DM, DIN, nullptr);
    }

    rmsnorm_kernel<<<L_SEQ, 256, 0, stream>>>(x, norm_f_w, h);

    // logits = h @ emb^T  (2048 x 32000, K=768)
    gemm_tn<0><<<dim3(NVOCAB / 64, L_SEQ / 64), 256, 0, stream>>>(
        h, DM, emb, DM, out, NVOCAB, L_SEQ, NVOCAB, DM, nullptr);
}